// Round 12
// baseline (164.024 us; speedup 1.0000x reference)
//
#include <hip/hip_runtime.h>

// SoftAttentionAlignment B=8, L=2048, D=128 fp32. MFMA flash attention, both dirs.
// R17 = R16 resubmitted verbatim (R16 round was an infra failure: "container
//       failed twice", no kernel signal; static audit clean — see journal).
// K-direct structure:
//   - K NEVER touches LDS: both waves of a group need IDENTICAL K fragments ->
//     read direct from the f16 prepass array into double-buffered regs (aKA/aKB,
//     prefetched one tile ahead; 16x64B lines/wave-load, L1/L2-served for wave 2).
//   - removes per group-tile: 4 ds_writes/thread, 16KB LDS reads, ALL K bank
//     conflicts (mod-128-collapse was ~8-way, unfixable). LDS vol/tile 48->24KB.
//   - V stays LDS-staged (write d-contig, read d-contig: conflict-free).
//   - bijective XCD swizzle (512 wgs): swz=(lid&7)*64+(lid>>3) = dir*256+bi*32+ix;
//     64 consecutive swz per XCD -> one dir, 2 bi (~3MB < 4MB L2).
// Evidence: R11 61.6us w/ MfmaUtil 22/VALU 23/conflicts 4.2M; R12 dbuf neutral;
// R13/R14: occupancy not the lever. LDS pipe volume+conflicts = remaining wall.

typedef __bf16    bf16;
typedef _Float16  f16;
typedef __bf16    bf16x4 __attribute__((ext_vector_type(4)));
typedef _Float16  f16x4  __attribute__((ext_vector_type(4)));
typedef __bf16    bf16x8 __attribute__((ext_vector_type(8)));
typedef _Float16  f16x8  __attribute__((ext_vector_type(8)));
typedef float     floatx4 __attribute__((ext_vector_type(4)));
typedef unsigned int uintx4 __attribute__((ext_vector_type(4)));

#define NB 8
#define SL 2048
#define TI 64
#define NT 32            // 32 j-tiles of 32 per group (group owns 1024 j)

#define F16SZ (NB * SL * 128 * 2)   // 4,194,304 B per converted array

#define SVT_S  32    // bf16 elems per d-row (64 B)

// per-group: sVT [128][32] bf16 = 8192 B
#define GSPAN    8192            // x2 groups = 16384
#define OFF_L    33792           // float[64]
#define LDS_BYTES 34048          // aOut fp32 [64][132] = 33792 overlaps group bufs

// ---------------- prepass: fp32 -> f16 (same layout) + bf16 transposed ----------
__global__ __launch_bounds__(256)
void prepass_cvt(const float* __restrict__ x1, const float* __restrict__ x2,
                 char* __restrict__ ws)
{
    __shared__ float tile[64 * 129];
    const int tid = threadIdx.x;
    const int j0  = blockIdx.x * 64;
    const int b   = blockIdx.y;
    const int z   = blockIdx.z;
    const float* src = z ? x2 : x1;
    f16*  oF = (f16*) (ws + (size_t)z * F16SZ);
    bf16* oT = (bf16*)(ws + 2 * (size_t)F16SZ + (size_t)z * F16SZ);

    #pragma unroll
    for (int n = 0; n < 8; ++n) {
        int ci = n * 256 + tid;              // 0..2047
        int row = ci >> 5, c4 = ci & 31;
        const float4 v = *(const float4*)(src + ((size_t)b * SL + j0 + row) * 128 + c4 * 4);
        tile[row * 129 + c4 * 4 + 0] = v.x;
        tile[row * 129 + c4 * 4 + 1] = v.y;
        tile[row * 129 + c4 * 4 + 2] = v.z;
        tile[row * 129 + c4 * 4 + 3] = v.w;
        f16x4 h; h[0] = (f16)v.x; h[1] = (f16)v.y; h[2] = (f16)v.z; h[3] = (f16)v.w;
        *(f16x4*)(oF + ((size_t)b * SL + j0 + row) * 128 + c4 * 4) = h;
    }
    __syncthreads();
    #pragma unroll
    for (int n = 0; n < 8; ++n) {
        int fi = n * 256 + tid;              // 0..2047
        int jg = fi & 15, d = fi >> 4;
        bf16x4 o;
        #pragma unroll
        for (int i = 0; i < 4; ++i) o[i] = (bf16)tile[(jg * 4 + i) * 129 + d];
        *(bf16x4*)(oT + ((size_t)b * 128 + d) * SL + j0 + jg * 4) = o;
    }
}

// ---------------- main kernel -----------------------------------------------
// One tile iteration; AKC = current K frags (ready), AKN = next (prefetched here).
#define TILE_BODY(T, AKC, AKN)                                                     \
    {                                                                              \
        __syncthreads(); /* (A) prev tile's V reads done before restage */         \
        _Pragma("unroll")                                                          \
        for (int n = 0; n < 4; ++n)                                                \
            *(bf16x8*)(sVT + (dV0 + n * 32) * SVT_S + jcV * 8) = vreg[n];          \
        __syncthreads(); /* (B) V tile staged */                                   \
        if ((T) < NT - 1) {                                                        \
            const f16*  kb = kfp + (size_t)((T) + 1) * 32 * 128;                   \
            const bf16* vb = vTf + (size_t)((T) + 1) * 32;                         \
            _Pragma("unroll")                                                      \
            for (int h = 0; h < 2; ++h)                                            \
                _Pragma("unroll")                                                  \
                for (int kk = 0; kk < 4; ++kk)                                     \
                    AKN[h * 4 + kk] = *(const f16x8*)(kb + h * 2048 + kk * 32);    \
            _Pragma("unroll")                                                      \
            for (int n = 0; n < 4; ++n)                                            \
                vreg[n] = *(const bf16x8*)(vb + (size_t)n * 32 * SL);              \
        }                                                                          \
        floatx4 Sf[2][2];                                                          \
        Sf[0][0] = (floatx4){0.f,0.f,0.f,0.f}; Sf[0][1] = (floatx4){0.f,0.f,0.f,0.f}; \
        Sf[1][0] = (floatx4){0.f,0.f,0.f,0.f}; Sf[1][1] = (floatx4){0.f,0.f,0.f,0.f}; \
        __builtin_amdgcn_s_setprio(1);                                             \
        _Pragma("unroll")                                                          \
        for (int kk = 0; kk < 4; ++kk) {                                           \
            Sf[0][0] = __builtin_amdgcn_mfma_f32_16x16x32_f16(AKC[kk],     aQ[kk],  Sf[0][0], 0, 0, 0); \
            Sf[0][1] = __builtin_amdgcn_mfma_f32_16x16x32_f16(AKC[4 + kk], aQ[kk],  Sf[0][1], 0, 0, 0); \
            Sf[1][0] = __builtin_amdgcn_mfma_f32_16x16x32_f16(AKC[kk],     aQ2[kk], Sf[1][0], 0, 0, 0); \
            Sf[1][1] = __builtin_amdgcn_mfma_f32_16x16x32_f16(AKC[4 + kk], aQ2[kk], Sf[1][1], 0, 0, 0); \
        }                                                                          \
        __builtin_amdgcn_s_setprio(0);                                             \
        bf16x8 aP0, aP1;                                                           \
        {                                                                          \
            float p00 = __expf(Sf[0][0][0]), p01 = __expf(Sf[0][0][1]);            \
            float p02 = __expf(Sf[0][0][2]), p03 = __expf(Sf[0][0][3]);            \
            float p10 = __expf(Sf[0][1][0]), p11 = __expf(Sf[0][1][1]);            \
            float p12 = __expf(Sf[0][1][2]), p13 = __expf(Sf[0][1][3]);            \
            l_acc += ((p00 + p01) + (p02 + p03)) + ((p10 + p11) + (p12 + p13));    \
            unsigned int A0, B0, A1, B1;                                           \
            asm("v_cvt_pk_bf16_f32 %0, %1, %2" : "=v"(A0) : "v"(p00), "v"(p01));   \
            asm("v_cvt_pk_bf16_f32 %0, %1, %2" : "=v"(B0) : "v"(p02), "v"(p03));   \
            asm("v_cvt_pk_bf16_f32 %0, %1, %2" : "=v"(A1) : "v"(p10), "v"(p11));   \
            asm("v_cvt_pk_bf16_f32 %0, %1, %2" : "=v"(B1) : "v"(p12), "v"(p13));   \
            asm("v_permlane32_swap_b32 %0, %1" : "+v"(A0), "+v"(A1));              \
            asm("v_permlane16_swap_b32 %0, %1" : "+v"(A0), "+v"(A1));              \
            asm("v_permlane32_swap_b32 %0, %1" : "+v"(B0), "+v"(B1));              \
            asm("v_permlane16_swap_b32 %0, %1" : "+v"(B0), "+v"(B1));              \
            uintx4 fr; fr.x = A0; fr.y = B0; fr.z = A1; fr.w = B1;                 \
            aP0 = __builtin_bit_cast(bf16x8, fr);                                  \
        }                                                                          \
        {                                                                          \
            float p00 = __expf(Sf[1][0][0]), p01 = __expf(Sf[1][0][1]);            \
            float p02 = __expf(Sf[1][0][2]), p03 = __expf(Sf[1][0][3]);            \
            float p10 = __expf(Sf[1][1][0]), p11 = __expf(Sf[1][1][1]);            \
            float p12 = __expf(Sf[1][1][2]), p13 = __expf(Sf[1][1][3]);            \
            l_acc2 += ((p00 + p01) + (p02 + p03)) + ((p10 + p11) + (p12 + p13));   \
            unsigned int A0, B0, A1, B1;                                           \
            asm("v_cvt_pk_bf16_f32 %0, %1, %2" : "=v"(A0) : "v"(p00), "v"(p01));   \
            asm("v_cvt_pk_bf16_f32 %0, %1, %2" : "=v"(B0) : "v"(p02), "v"(p03));   \
            asm("v_cvt_pk_bf16_f32 %0, %1, %2" : "=v"(A1) : "v"(p10), "v"(p11));   \
            asm("v_cvt_pk_bf16_f32 %0, %1, %2" : "=v"(B1) : "v"(p12), "v"(p13));   \
            asm("v_permlane32_swap_b32 %0, %1" : "+v"(A0), "+v"(A1));              \
            asm("v_permlane16_swap_b32 %0, %1" : "+v"(A0), "+v"(A1));              \
            asm("v_permlane32_swap_b32 %0, %1" : "+v"(B0), "+v"(B1));              \
            asm("v_permlane16_swap_b32 %0, %1" : "+v"(B0), "+v"(B1));              \
            uintx4 fr; fr.x = A0; fr.y = B0; fr.z = A1; fr.w = B1;                 \
            aP1 = __builtin_bit_cast(bf16x8, fr);                                  \
        }                                                                          \
        __builtin_amdgcn_s_setprio(1);                                             \
        _Pragma("unroll")                                                          \
        for (int nd = 0; nd < 8; ++nd) {                                           \
            bf16x8 bV = *(const bf16x8*)(sVT + (nd * 16 + lr) * SVT_S + lq * 8);   \
            Oacc[nd]  = __builtin_amdgcn_mfma_f32_16x16x32_bf16(aP0, bV, Oacc[nd],  0, 0, 0); \
            Oacc2[nd] = __builtin_amdgcn_mfma_f32_16x16x32_bf16(aP1, bV, Oacc2[nd], 0, 0, 0); \
        }                                                                          \
        __builtin_amdgcn_s_setprio(0);                                             \
    }

__global__ __launch_bounds__(256, 2)
void soft_attn_align_mfma(const float* __restrict__ x1,
                          const float* __restrict__ x2,
                          const char* __restrict__ ws,
                          float* __restrict__ out)
{
    __shared__ __align__(16) char lds_raw[LDS_BYTES];

    const int tid  = threadIdx.x;
    const int lane = tid & 63;
    const int wv   = tid >> 6;          // 0..3
    const int g    = wv >> 1;           // j-half group
    const int rowbase = (wv & 1) * 32;  // wave's 32 q-rows (two 16-row blocks)
    const int lr   = lane & 15;
    const int lq   = lane >> 4;
    const int t128 = tid & 127;         // thread id within group

    bf16* sVT  = (bf16*)(lds_raw + g * GSPAN);   // [128][32] bf16 d-major (d, j)
    float* aOut = (float*)(lds_raw);             // [64][132] fp32
    float* sL   = (float*)(lds_raw + OFF_L);

    // bijective XCD swizzle for 512 wgs: swz = dir*256 + bi*32 + ix
    const int lid = blockIdx.x + 32 * (blockIdx.y + 8 * blockIdx.z);  // 0..511
    const int swz = (lid & 7) * 64 + (lid >> 3);                      // 0..511
    const int ix  = swz & 31;
    const int bi  = (swz >> 5) & 7;
    const int dir = swz >> 8;
    const int i0  = ix * TI;

    const float* xq = dir ? x2 : x1;                     // epilogue (exact fp32)
    const f16*  x1f = (const f16*)(ws);
    const f16*  x2f = (const f16*)(ws + F16SZ);
    const bf16* x1T = (const bf16*)(ws + 2 * (size_t)F16SZ);
    const bf16* x2T = (const bf16*)(ws + 3 * (size_t)F16SZ);
    const f16*  xqf  = dir ? x2f : x1f;
    const f16*  xkvf = dir ? x1f : x2f;
    const bf16* xvT  = dir ? x1T : x2T;

    // ---- Q fragments (f16): two row-blocks (rows rowbase+lr, rowbase+16+lr) ----
    f16x8 aQ[4], aQ2[4];
    {
        const f16* qrow0 = xqf + ((size_t)bi * SL + i0 + rowbase + 0  + lr) * 128;
        const f16* qrow1 = xqf + ((size_t)bi * SL + i0 + rowbase + 16 + lr) * 128;
        #pragma unroll
        for (int kk = 0; kk < 4; ++kk) {
            aQ[kk]  = *(const f16x8*)(qrow0 + kk * 32 + lq * 8);
            aQ2[kk] = *(const f16x8*)(qrow1 + kk * 32 + lq * 8);
        }
    }
    float l_acc = 0.0f, l_acc2 = 0.0f;
    floatx4 Oacc[8], Oacc2[8];
    #pragma unroll
    for (int nd = 0; nd < 8; ++nd) {
        Oacc[nd]  = (floatx4){0.f, 0.f, 0.f, 0.f};
        Oacc2[nd] = (floatx4){0.f, 0.f, 0.f, 0.f};
    }

    // V staging (coalesced): d = t128>>2, 8-bf16 chunk = t128&3
    const int dV0 = t128 >> 2, jcV = t128 & 3;
    const bf16* vTf = xvT + ((size_t)bi * 128 + dV0) * SL + g * 1024 + jcV * 8;
    // K-frag per-lane base: row = g*1024 + t*32 + h*16 + lr, col = kk*32 + lq*8
    const f16* kfp = xkvf + ((size_t)bi * SL + g * 1024 + lr) * 128 + lq * 8;

    f16x8  aKA[8], aKB[8];
    bf16x8 vreg[4];
    // prologue: K frags tile 0 -> aKA ; V tile 0 -> vreg
    #pragma unroll
    for (int h = 0; h < 2; ++h)
        #pragma unroll
        for (int kk = 0; kk < 4; ++kk)
            aKA[h * 4 + kk] = *(const f16x8*)(kfp + h * 2048 + kk * 32);
    #pragma unroll
    for (int n = 0; n < 4; ++n)
        vreg[n] = *(const bf16x8*)(vTf + (size_t)n * 32 * SL);

    for (int t = 0; t < NT; t += 2) {
        TILE_BODY(t,     aKA, aKB)
        TILE_BODY(t + 1, aKB, aKA)
    }

    // ---- row sums (rb0: rows rowbase+lr ; rb1: rows rowbase+16+lr) ----
    float l_row[2][4];
    {
        float lv = l_acc;
        lv += __shfl_xor(lv, 16, 64);
        lv += __shfl_xor(lv, 32, 64);
        #pragma unroll
        for (int r = 0; r < 4; ++r) l_row[0][r] = __shfl(lv, lq * 4 + r, 64);
        lv = l_acc2;
        lv += __shfl_xor(lv, 16, 64);
        lv += __shfl_xor(lv, 32, 64);
        #pragma unroll
        for (int r = 0; r < 4; ++r) l_row[1][r] = __shfl(lv, lq * 4 + r, 64);
    }

    __syncthreads();   // all tile-buffer reads done before combine overwrites LDS

    // ---- combine j-halves: group 1 publishes partials, group 0 merges ----
    if (g == 1) {
        #pragma unroll
        for (int r = 0; r < 4; ++r) {
            int row0 = rowbase + lq * 4 + r;
            int row1 = rowbase + 16 + lq * 4 + r;
            #pragma unroll
            for (int nd = 0; nd < 8; ++nd) {
                aOut[row0 * 132 + nd * 16 + lr] = Oacc[nd][r];
                aOut[row1 * 132 + nd * 16 + lr] = Oacc2[nd][r];
            }
            if (lr == 0) { sL[row0] = l_row[0][r]; sL[row1] = l_row[1][r]; }
        }
    }
    __syncthreads();
    if (g == 0) {
        #pragma unroll
        for (int r = 0; r < 4; ++r) {
            int row0 = rowbase + lq * 4 + r;
            int row1 = rowbase + 16 + lq * 4 + r;
            float inv0 = 1.0f / (l_row[0][r] + sL[row0]);
            float inv1 = 1.0f / (l_row[1][r] + sL[row1]);
            #pragma unroll
            for (int nd = 0; nd < 8; ++nd) {
                int idx0 = row0 * 132 + nd * 16 + lr;
                int idx1 = row1 * 132 + nd * 16 + lr;
                aOut[idx0] = (Oacc[nd][r]  + aOut[idx0]) * inv0;
                aOut[idx1] = (Oacc2[nd][r] + aOut[idx1]) * inv1;
            }
        }
    }
    __syncthreads();

    // ---- epilogue: out row = [q, A, q-A, q*A], q exact fp32 from global ----
    float* outb = out + ((size_t)dir * NB * SL + (size_t)bi * SL + i0) * 512;
    #pragma unroll
    for (int k = 0; k < 8; ++k) {
        int s = tid + 256 * k;          // 2048 slots: row (0..63), c4 (0..31)
        int r = s >> 5, c4 = s & 31;
        float4 a = *(const float4*)(aOut + r * 132 + c4 * 4);
        float4 q = *(const float4*)(xq + ((size_t)bi * SL + i0 + r) * 128 + c4 * 4);
        float4 d, m;
        d.x = q.x - a.x; d.y = q.y - a.y; d.z = q.z - a.z; d.w = q.w - a.w;
        m.x = q.x * a.x; m.y = q.y * a.y; m.z = q.z * a.z; m.w = q.w * a.w;
        float4* orow = (float4*)(outb + (size_t)r * 512);
        orow[c4]      = q;
        orow[32 + c4] = a;
        orow[64 + c4] = d;
        orow[96 + c4] = m;
    }
}

extern "C" void kernel_launch(void* const* d_in, const int* in_sizes, int n_in,
                              void* d_out, int out_size, void* d_ws, size_t ws_size,
                              hipStream_t stream) {
    const float* x1 = (const float*)d_in[0];
    const float* x2 = (const float*)d_in[1];
    float* out = (float*)d_out;
    (void)in_sizes; (void)n_in; (void)out_size; (void)ws_size;

    dim3 pgrid(SL / 64, NB, 2);
    prepass_cvt<<<pgrid, dim3(256), 0, stream>>>(x1, x2, (char*)d_ws);

    dim3 grid(SL / TI, NB, 2);
    soft_attn_align_mfma<<<grid, dim3(256), 0, stream>>>(x1, x2, (const char*)d_ws, out);
}